// Round 15
// baseline (224.928 us; speedup 1.0000x reference)
//
#include <hip/hip_runtime.h>

// ---------------------------------------------------------------------------
// SageCox: 4-layer GraphSAGE (mean aggr), N=100000, E=640000.
// out = mean_neigh(x)@Wl + bl + x@Wr per layer.
// Restructured: p = x@Wl ; acc = bf16(x@Wr + bl) ; x_next = bf16(acc + invdeg*sum p[src]).
// proj = MFMA bf16 (16x16x32, f32 accum), per-phase W staging in LDS, 2-phase
// coalesced bf16x8 epilogue. CSR fill XCD-partitioned and fused with projm L0
// with ROLE-INTERLEAVED grid (16-block groups: slots 0-8 fill, 9-15 projm) so
// each CU holds a mix of fill waves (memory/atomic pipe) and projm waves
// (MFMA pipe) -> true overlap instead of phase serialization.
// Gather: CSR, paired-uint loads, 4-edge unroll, L1 2 nodes/wave.
// p/acc/xnext rows padded to 96/64/32 elems. L3 GEMV fused into L2 gather.
// ---------------------------------------------------------------------------

#define NNODES 100000
#define NEDGES 640000
#define GROUPS 112      // 16-block groups: 9 fill + 7 projm slots each
#define FPG 9           // fill slots per group -> 1008 fill blocks
                        // proj slots: 112*7 = 784 >= 782 needed

using bf16x8 = __attribute__((ext_vector_type(8))) short;
using f32x4  = __attribute__((ext_vector_type(4))) float;

__device__ __forceinline__ unsigned short f2bf(float f) {
    union { float f; unsigned u; } v; v.f = f;
    unsigned r = v.u + 0x7fffu + ((v.u >> 16) & 1u);
    return (unsigned short)(r >> 16);
}
__device__ __forceinline__ float bf2f(unsigned b) {
    union { unsigned u; float f; } v; v.u = b << 16;
    return v.f;
}

// ---- weight pack helper ---------------------------------------------------

__device__ __forceinline__ void packT_one(const float* Wl, const float* Wr,
                                          unsigned short* WcT, int idx, int DIN,
                                          int KP, int DOUT, int DOUTP) {
    int c = idx / KP, k = idx - c * KP;
    float v = 0.0f;
    if (k < DIN) {
        if (c < DOUT) v = Wl[k * DOUT + c];
        else if (c >= DOUTP && c < DOUTP + DOUT) v = Wr[k * DOUT + (c - DOUTP)];
    }
    WcT[idx] = f2bf(v);
}

// ---- fused: packAll (blocks [0,PACKB)) || hist (rest) ---------------------

#define PACKB 160

__global__ void packhist_kernel(const float* __restrict__ Wl0, const float* __restrict__ Wr0,
                                const float* __restrict__ Wl1, const float* __restrict__ Wr1,
                                const float* __restrict__ Wl2, const float* __restrict__ Wr2,
                                unsigned short* __restrict__ Wc0,
                                unsigned short* __restrict__ Wc1,
                                unsigned short* __restrict__ Wc2,
                                const int* __restrict__ edst, int* __restrict__ deg, int E) {
    const int S0 = 192 * 128, S1 = 128 * 96, S2 = 64 * 64;
    if (blockIdx.x < PACKB) {
        int idx = blockIdx.x * 256 + threadIdx.x;
        if (idx < S0) packT_one(Wl0, Wr0, Wc0, idx, 128, 128, 85, 96);
        else if (idx < S0 + S1) packT_one(Wl1, Wr1, Wc1, idx - S0, 85, 96, 56, 64);
        else if (idx < S0 + S1 + S2) packT_one(Wl2, Wr2, Wc2, idx - S0 - S1, 56, 64, 28, 32);
    } else {
        int i = (blockIdx.x - PACKB) * 256 + threadIdx.x;
        if (i < E) atomicAdd(&deg[edst[i]], 1);
    }
}

// ---- scans ----------------------------------------------------------------

__global__ void scanA_kernel(const int* __restrict__ deg, int* __restrict__ bsum, int N) {
    __shared__ int s[256];
    int i = blockIdx.x * 256 + threadIdx.x;
    s[threadIdx.x] = (i < N) ? deg[i] : 0;
    __syncthreads();
    for (int off = 128; off > 0; off >>= 1) {
        if (threadIdx.x < off) s[threadIdx.x] += s[threadIdx.x + off];
        __syncthreads();
    }
    if (threadIdx.x == 0) bsum[blockIdx.x] = s[0];
}

// scanC with inlined block-prefix: each block sums bsum[0..blockIdx.x).
__global__ void scanC_kernel(const int* __restrict__ deg, const int* __restrict__ bsum,
                             int* __restrict__ rowptr, int* __restrict__ cursor, int N, int E) {
    __shared__ int s[256];
    int t = threadIdx.x;

    int a = 0;
    for (int j = t; j < blockIdx.x; j += 256) a += bsum[j];
    s[t] = a;
    __syncthreads();
    for (int off = 128; off > 0; off >>= 1) {
        if (t < off) s[t] += s[t + off];
        __syncthreads();
    }
    const int base = s[0];
    __syncthreads();

    int i = blockIdx.x * 256 + t;
    int v = (i < N) ? deg[i] : 0;
    s[t] = v;
    __syncthreads();
    for (int off = 1; off < 256; off <<= 1) {
        int add = (t >= off) ? s[t - off] : 0;
        __syncthreads();
        s[t] += add;
        __syncthreads();
    }
    if (i < N) {
        int excl = base + s[t] - v;
        rowptr[i] = excl;
        cursor[i] = excl;
        if (i == N - 1) rowptr[N] = E;
    }
}

// ---- MFMA projection body: per-phase W in LDS + 2-phase epilogue ----------

template <bool XFP32, int KP, int SIN, int NTILES, int DOUT, int SPP>
__device__ __forceinline__ void
projm_body(int bid, const void* __restrict__ xin,
           const unsigned short* __restrict__ WcT,
           const float* __restrict__ bl,
           unsigned short* __restrict__ p,
           unsigned short* __restrict__ acc_out, int N) {
    constexpr int KT   = KP / 32;
    constexpr int HT   = NTILES / 2;
    constexpr int WSTR = KP + 8;
    constexpr int LSTR = SPP + 8;
    static_assert(HT * 16 == SPP, "phase width must equal SPP");
    __shared__ short wS[HT * 16 * WSTR];
    __shared__ short oS[128 * LSTR];

    const int lane = threadIdx.x & 63;
    const int wave = threadIdx.x >> 6;
    const int l15 = lane & 15;
    const int lk  = lane >> 4;
    const int row0 = bid * 128;
    const int wrow = wave * 32;

    auto stageW = [&](int colbase) {
        for (int c8 = threadIdx.x; c8 < HT * 16 * (KP / 8); c8 += 256) {
            const int c  = c8 / (KP / 8);
            const int k8 = c8 - c * (KP / 8);
            *(bf16x8*)(wS + c * WSTR + k8 * 8) =
                *(const bf16x8*)(WcT + (size_t)(colbase + c) * KP + k8 * 8);
        }
    };

    stageW(0);

    bf16x8 afrag[2][KT];
#pragma unroll
    for (int h = 0; h < 2; ++h) {
        int arow = row0 + wrow + h * 16 + l15;
        if (arow >= N) arow = N - 1;
        if constexpr (XFP32) {
            const float* xr = (const float*)xin + (size_t)arow * SIN + lk * 8;
#pragma unroll
            for (int kt = 0; kt < KT; ++kt) {
                const float4 a = *(const float4*)(xr + kt * 32);
                const float4 b = *(const float4*)(xr + kt * 32 + 4);
                bf16x8 v;
                v[0] = (short)f2bf(a.x); v[1] = (short)f2bf(a.y);
                v[2] = (short)f2bf(a.z); v[3] = (short)f2bf(a.w);
                v[4] = (short)f2bf(b.x); v[5] = (short)f2bf(b.y);
                v[6] = (short)f2bf(b.z); v[7] = (short)f2bf(b.w);
                afrag[h][kt] = v;
            }
        } else {
            const unsigned short* xr = (const unsigned short*)xin + (size_t)arow * SIN + lk * 8;
#pragma unroll
            for (int kt = 0; kt < KT; ++kt)
                afrag[h][kt] = *(const bf16x8*)(xr + kt * 32);
        }
    }

    __syncthreads();

    const int rows_here = min(128, N - row0);
    const int cnt8 = rows_here * (SPP / 8);

    auto computePhase = [&](bool withBias) {
#pragma unroll 2
        for (int nt = 0; nt < HT; ++nt) {
            const short* wp = wS + (size_t)(nt * 16 + l15) * WSTR + lk * 8;
            bf16x8 bfrag[KT];
#pragma unroll
            for (int kt = 0; kt < KT; ++kt)
                bfrag[kt] = *(const bf16x8*)(wp + kt * 32);

            f32x4 a0 = {0.f, 0.f, 0.f, 0.f};
            f32x4 a1 = {0.f, 0.f, 0.f, 0.f};
#pragma unroll
            for (int kt = 0; kt < KT; ++kt) {
                a0 = __builtin_amdgcn_mfma_f32_16x16x32_bf16(afrag[0][kt], bfrag[kt], a0, 0, 0, 0);
                a1 = __builtin_amdgcn_mfma_f32_16x16x32_bf16(afrag[1][kt], bfrag[kt], a1, 0, 0, 0);
            }

            const int co = nt * 16 + l15;
            const float bias = (withBias && co < DOUT) ? bl[co] : 0.0f;
#pragma unroll
            for (int h = 0; h < 2; ++h) {
                const f32x4 a = h ? a1 : a0;
                const int rl = wrow + h * 16 + lk * 4;
#pragma unroll
                for (int j = 0; j < 4; ++j)
                    oS[(rl + j) * LSTR + co] = (short)f2bf(a[j] + bias);
            }
        }
    };

    auto storeOut = [&](unsigned short* dst) {
        for (int e8 = threadIdx.x; e8 < cnt8; e8 += 256) {
            const int row = e8 / (SPP / 8);
            const int c8  = e8 - row * (SPP / 8);
            *(bf16x8*)(dst + (size_t)row0 * SPP + (size_t)e8 * 8) =
                *(const bf16x8*)(oS + row * LSTR + c8 * 8);
        }
    };

    computePhase(false);
    __syncthreads();
    storeOut(p);
    stageW(HT * 16);
    __syncthreads();
    computePhase(true);
    __syncthreads();
    storeOut(acc_out);
}

template <bool XFP32, int KP, int SIN, int NTILES, int DOUT, int SPP>
__global__ void __launch_bounds__(256)
projm_kernel(const void* __restrict__ xin,
             const unsigned short* __restrict__ WcT,
             const float* __restrict__ bl,
             unsigned short* __restrict__ p,
             unsigned short* __restrict__ acc_out, int N) {
    projm_body<XFP32, KP, SIN, NTILES, DOUT, SPP>(blockIdx.x, xin, WcT, bl, p, acc_out, N);
}

// ---- fused, ROLE-INTERLEAVED: fill (slots 0-8 of each 16-group) || projm --
// Fill partition = slot&7 (tracks bid%8 ~ XCD); partition 0 gets 2 sub-blocks
// per group (slots 0 and 8), partitions 1-7 get 1. Each partition grid-strides
// the full edge list with its own sub count -> every edge written once.

__global__ void __launch_bounds__(256)
projfill_kernel(const float* __restrict__ x,
                const unsigned short* __restrict__ Wc0,
                const float* __restrict__ bl0,
                unsigned short* __restrict__ p,
                unsigned short* __restrict__ acc_out, int N,
                const int* __restrict__ esrc, const int* __restrict__ edst,
                int* __restrict__ cursor, int* __restrict__ csr, int E) {
    const int g = blockIdx.x >> 4;
    const int s = blockIdx.x & 15;
    if (s < FPG) {
        const int part = s & 7;
        int sub, nsub;
        if (part == 0) { sub = g * 2 + (s >> 3); nsub = GROUPS * 2; }
        else           { sub = g;                nsub = GROUPS;     }
        const int chunk = N >> 3;
        const int lo = part * chunk;
        const int hi = (part == 7) ? N : lo + chunk;
        for (int i = sub * 256 + threadIdx.x; i < E; i += nsub * 256) {
            const int d = edst[i];
            if (d >= lo && d < hi) {
                int pos = atomicAdd(&cursor[d], 1);
                csr[pos] = esrc[i];
            }
        }
        return;
    }
    const int po = g * (16 - FPG) + (s - FPG);
    if (po >= (NNODES + 127) / 128) return;
    projm_body<true, 128, 128, 12, 85, 96>(po, x, Wc0, bl0, p, acc_out, N);
}

// ---- gather: x_next = bf16(acc + invdeg * sum p[src]) ---------------------

template <int DOUT, int SP, int SN, int NPW>
__global__ void __launch_bounds__(256)
gatherb_kernel(const int* __restrict__ rowptr, const int* __restrict__ csr,
               const unsigned short* __restrict__ p, const unsigned short* __restrict__ acc,
               unsigned short* __restrict__ xnext, int N) {
    const int wid  = (blockIdx.x * 256 + threadIdx.x) >> 6;
    const int lane = threadIdx.x & 63;
    int node, hl;
    if constexpr (NPW == 1) {
        node = __builtin_amdgcn_readfirstlane(wid);
        hl = lane;
    } else {
        node = wid * 2 + (lane >> 5);
        hl = lane & 31;
    }
    if (node >= N) return;
    const int beg = rowptr[node], end = rowptr[node + 1];
    const float inv = 1.0f / (float)max(end - beg, 1);
    constexpr int NPAIR = (DOUT + 1) / 2;
    const int co = 2 * hl;

    float s0 = 0.f, s1 = 0.f, s2 = 0.f, s3 = 0.f;
    float h0 = 0.f, h1 = 0.f, h2 = 0.f, h3 = 0.f;
    if (hl < NPAIR) {
        int j = beg;
        for (; j + 4 <= end; j += 4) {
            const unsigned u0 = *(const unsigned*)(p + (size_t)csr[j]     * SP + co);
            const unsigned u1 = *(const unsigned*)(p + (size_t)csr[j + 1] * SP + co);
            const unsigned u2 = *(const unsigned*)(p + (size_t)csr[j + 2] * SP + co);
            const unsigned u3 = *(const unsigned*)(p + (size_t)csr[j + 3] * SP + co);
            s0 += bf2f(u0 & 0xffffu); h0 += bf2f(u0 >> 16);
            s1 += bf2f(u1 & 0xffffu); h1 += bf2f(u1 >> 16);
            s2 += bf2f(u2 & 0xffffu); h2 += bf2f(u2 >> 16);
            s3 += bf2f(u3 & 0xffffu); h3 += bf2f(u3 >> 16);
        }
        for (; j < end; ++j) {
            const unsigned u0 = *(const unsigned*)(p + (size_t)csr[j] * SP + co);
            s0 += bf2f(u0 & 0xffffu); h0 += bf2f(u0 >> 16);
        }
    }
    if (co < SN) {
        const float slo = (s0 + s1) + (s2 + s3);
        const float shi = (h0 + h1) + (h2 + h3);
        float lo = 0.f, hi = 0.f;
        if (co < DOUT)     lo = bf2f((unsigned)acc[(size_t)node * SP + co])     + inv * slo;
        if (co + 1 < DOUT) hi = bf2f((unsigned)acc[(size_t)node * SP + co + 1]) + inv * shi;
        const unsigned w = (unsigned)f2bf(lo) | ((unsigned)f2bf(hi) << 16);
        *(unsigned*)(xnext + (size_t)node * SN + co) = w;
    }
}

// ---- layer-2 gather fused with layer-3 GEMV (28 -> 1), 2 nodes/wave -------

__global__ void __launch_bounds__(256)
gather2g_kernel(const int* __restrict__ rowptr, const int* __restrict__ csr,
                const unsigned short* __restrict__ p, const unsigned short* __restrict__ acc,
                const float* __restrict__ Wl3, const float* __restrict__ bl3,
                const float* __restrict__ Wr3,
                float* __restrict__ p3, float* __restrict__ out, int N) {
    const int wid  = (blockIdx.x * 256 + threadIdx.x) >> 6;
    const int lane = threadIdx.x & 63;
    const int node = wid * 2 + (lane >> 5);
    const int hl   = lane & 31;
    if (node >= N) return;
    const int beg = rowptr[node], end = rowptr[node + 1];
    const float inv = 1.0f / (float)max(end - beg, 1);
    const int co = 2 * hl;

    float s0 = 0.f, s1 = 0.f, s2 = 0.f, s3 = 0.f;
    float h0 = 0.f, h1 = 0.f, h2 = 0.f, h3 = 0.f;
    if (hl < 14) {
        int j = beg;
        for (; j + 4 <= end; j += 4) {
            const unsigned u0 = *(const unsigned*)(p + (size_t)csr[j]     * 32 + co);
            const unsigned u1 = *(const unsigned*)(p + (size_t)csr[j + 1] * 32 + co);
            const unsigned u2 = *(const unsigned*)(p + (size_t)csr[j + 2] * 32 + co);
            const unsigned u3 = *(const unsigned*)(p + (size_t)csr[j + 3] * 32 + co);
            s0 += bf2f(u0 & 0xffffu); h0 += bf2f(u0 >> 16);
            s1 += bf2f(u1 & 0xffffu); h1 += bf2f(u1 >> 16);
            s2 += bf2f(u2 & 0xffffu); h2 += bf2f(u2 >> 16);
            s3 += bf2f(u3 & 0xffffu); h3 += bf2f(u3 >> 16);
        }
        for (; j < end; ++j) {
            const unsigned u0 = *(const unsigned*)(p + (size_t)csr[j] * 32 + co);
            s0 += bf2f(u0 & 0xffffu); h0 += bf2f(u0 >> 16);
        }
    }
    float xlo = 0.f, xhi = 0.f, wl0 = 0.f, wl1 = 0.f, wr0 = 0.f, wr1 = 0.f;
    if (hl < 14) {
        xlo = bf2f((unsigned)acc[(size_t)node * 32 + co])     + inv * ((s0 + s1) + (s2 + s3));
        xhi = bf2f((unsigned)acc[(size_t)node * 32 + co + 1]) + inv * ((h0 + h1) + (h2 + h3));
        wl0 = Wl3[co]; wl1 = Wl3[co + 1];
        wr0 = Wr3[co]; wr1 = Wr3[co + 1];
    }
    float sl = xlo * wl0 + xhi * wl1;
    float sr = xlo * wr0 + xhi * wr1;
#pragma unroll
    for (int off = 16; off > 0; off >>= 1) {
        sl += __shfl_xor(sl, off, 64);
        sr += __shfl_xor(sr, off, 64);
    }
    if (hl == 0) {
        p3[node] = sl;
        out[node] = sr + bl3[0];
    }
}

__global__ void gather1_kernel(const int* __restrict__ rowptr, const int* __restrict__ csr,
                               const float* __restrict__ p, float* __restrict__ out, int N) {
    const int node = blockIdx.x * blockDim.x + threadIdx.x;
    if (node >= N) return;
    const int beg = rowptr[node], end = rowptr[node + 1];
    const float inv = 1.0f / (float)max(end - beg, 1);
    float a0 = 0.f, a1 = 0.f, a2 = 0.f, a3 = 0.f;
    int j = beg;
    for (; j + 4 <= end; j += 4) {
        a0 += p[csr[j]]; a1 += p[csr[j + 1]]; a2 += p[csr[j + 2]]; a3 += p[csr[j + 3]];
    }
    for (; j < end; ++j) a0 += p[csr[j]];
    out[node] += inv * ((a0 + a1) + (a2 + a3));
}

// ---------------------------------------------------------------------------

extern "C" void kernel_launch(void* const* d_in, const int* in_sizes, int n_in,
                              void* d_out, int out_size, void* d_ws, size_t ws_size,
                              hipStream_t stream) {
    const float* x  = (const float*)d_in[0];
    const int*   ei = (const int*)d_in[1];
    const int N = NNODES;
    const int E = NEDGES;
    const int* esrc = ei;
    const int* edst = ei + E;

    const float* Wl[4] = {(const float*)d_in[2], (const float*)d_in[5],
                          (const float*)d_in[8], (const float*)d_in[11]};
    const float* bl[4] = {(const float*)d_in[3], (const float*)d_in[6],
                          (const float*)d_in[9], (const float*)d_in[12]};
    const float* Wr[4] = {(const float*)d_in[4], (const float*)d_in[7],
                          (const float*)d_in[10], (const float*)d_in[13]};

    // ---- workspace arena (byte offsets, 256B aligned) ----
    char* base = (char*)d_ws;
    size_t off = 0;
    auto alloc = [&](size_t bytes) {
        char* r = base + off;
        off += (bytes + 255) & ~(size_t)255;
        return r;
    };
    unsigned short* pB   = (unsigned short*)alloc((size_t)N * 96 * 2);
    unsigned short* accB = (unsigned short*)alloc((size_t)N * 96 * 2);
    unsigned short* xp   = (unsigned short*)alloc((size_t)N * 96 * 2);
    float*          p3   = (float*)alloc((size_t)N * 4);
    unsigned short* Wc0  = (unsigned short*)alloc((size_t)192 * 128 * 2);
    unsigned short* Wc1  = (unsigned short*)alloc((size_t)128 * 96 * 2);
    unsigned short* Wc2  = (unsigned short*)alloc((size_t)64 * 64 * 2);
    int* degi   = (int*)alloc((size_t)N * 4);
    int* rowptr = (int*)alloc((size_t)(N + 1) * 4);
    int* cursor = (int*)alloc((size_t)N * 4);
    int* csr    = (int*)alloc((size_t)E * 4);
    int* bsum   = (int*)alloc(512 * 4);

    unsigned short* x2 = xp;   // x1 dead after L1 proj; reuse region for x2

    const int nb = (N + 255) / 256;     // 391
    const int histB = (E + 255) / 256;  // 2500
    const int projBlocks = (N + 127) / 128;  // 782

    // degi = 0, then fused {packAll || hist}
    hipMemsetAsync(degi, 0, (size_t)N * sizeof(int), stream);
    packhist_kernel<<<PACKB + histB, 256, 0, stream>>>(
        Wl[0], Wr[0], Wl[1], Wr[1], Wl[2], Wr[2], Wc0, Wc1, Wc2, edst, degi, E);

    // scans (scanB folded into scanC)
    scanA_kernel<<<nb, 256, 0, stream>>>(degi, bsum, N);
    scanC_kernel<<<nb, 256, 0, stream>>>(degi, bsum, rowptr, cursor, N, E);

    // fused, role-interleaved {partitioned fill || projm L0}
    projfill_kernel<<<GROUPS * 16, 256, 0, stream>>>(
        x, Wc0, bl[0], pB, accB, N, esrc, edst, cursor, csr, E);
    gatherb_kernel<85, 96, 96, 1><<<(N + 3) / 4, 256, 0, stream>>>(
        rowptr, csr, pB, accB, xp, N);

    // Layer 1: K=96 (85 zero-padded), 8 tiles (4+4); p/acc stride 64
    projm_kernel<false, 96, 96, 8, 56, 64><<<projBlocks, 256, 0, stream>>>(
        xp, Wc1, bl[1], pB, accB, N);
    gatherb_kernel<56, 64, 64, 2><<<(N + 7) / 8, 256, 0, stream>>>(
        rowptr, csr, pB, accB, x2, N);

    // Layer 2: K=64 (56 zero-padded), 4 tiles (2+2); p/acc stride 32
    projm_kernel<false, 64, 64, 4, 28, 32><<<projBlocks, 256, 0, stream>>>(
        x2, Wc2, bl[2], pB, accB, N);

    // Layer-2 gather + layer-3 GEMV fused (2 nodes/wave); then scalar gather
    gather2g_kernel<<<(N + 7) / 8, 256, 0, stream>>>(
        rowptr, csr, pB, accB, Wl[3], bl[3], Wr[3], p3, (float*)d_out, N);
    gather1_kernel<<<(N + 255) / 256, 256, 0, stream>>>(
        rowptr, csr, p3, (float*)d_out, N);
}

// Round 16
// 216.709 us; speedup vs baseline: 1.0379x; 1.0379x over previous
//
#include <hip/hip_runtime.h>

// ---------------------------------------------------------------------------
// SageCox: 4-layer GraphSAGE (mean aggr), N=100000, E=640000.
// out = mean_neigh(x)@Wl + bl + x@Wr per layer.
// Restructured: p = x@Wl ; acc = bf16(x@Wr + bl) ; x_next = bf16(acc + invdeg*sum p[src]).
// proj = MFMA bf16 (16x16x32, f32 accum), per-phase W staging in LDS, 2-phase
// coalesced bf16x8 epilogue. CSR fill XCD-partitioned (bid%8 -> dst range),
// fused with projm L0: fill blocks [0,512) + projm after. FILLB=512 (not
// 1024) so the ~768 initially-resident blocks are 512 fill + 256 projm ->
// both roles co-resident from t=0 (round-15 lesson: slot-interleave inside
// one kernel starves LDS; count-based mix does not).
// Gather: CSR, paired-uint loads, 4-edge unroll, L1 2 nodes/wave.
// p/acc/xnext rows padded to 96/64/32 elems. L3 GEMV fused into L2 gather.
// ---------------------------------------------------------------------------

#define NNODES 100000
#define NEDGES 640000
#define FILLB 512

using bf16x8 = __attribute__((ext_vector_type(8))) short;
using f32x4  = __attribute__((ext_vector_type(4))) float;

__device__ __forceinline__ unsigned short f2bf(float f) {
    union { float f; unsigned u; } v; v.f = f;
    unsigned r = v.u + 0x7fffu + ((v.u >> 16) & 1u);
    return (unsigned short)(r >> 16);
}
__device__ __forceinline__ float bf2f(unsigned b) {
    union { unsigned u; float f; } v; v.u = b << 16;
    return v.f;
}

// ---- weight pack helper ---------------------------------------------------

__device__ __forceinline__ void packT_one(const float* Wl, const float* Wr,
                                          unsigned short* WcT, int idx, int DIN,
                                          int KP, int DOUT, int DOUTP) {
    int c = idx / KP, k = idx - c * KP;
    float v = 0.0f;
    if (k < DIN) {
        if (c < DOUT) v = Wl[k * DOUT + c];
        else if (c >= DOUTP && c < DOUTP + DOUT) v = Wr[k * DOUT + (c - DOUTP)];
    }
    WcT[idx] = f2bf(v);
}

// ---- fused: packAll (blocks [0,PACKB)) || hist (rest) ---------------------

#define PACKB 160

__global__ void packhist_kernel(const float* __restrict__ Wl0, const float* __restrict__ Wr0,
                                const float* __restrict__ Wl1, const float* __restrict__ Wr1,
                                const float* __restrict__ Wl2, const float* __restrict__ Wr2,
                                unsigned short* __restrict__ Wc0,
                                unsigned short* __restrict__ Wc1,
                                unsigned short* __restrict__ Wc2,
                                const int* __restrict__ edst, int* __restrict__ deg, int E) {
    const int S0 = 192 * 128, S1 = 128 * 96, S2 = 64 * 64;
    if (blockIdx.x < PACKB) {
        int idx = blockIdx.x * 256 + threadIdx.x;
        if (idx < S0) packT_one(Wl0, Wr0, Wc0, idx, 128, 128, 85, 96);
        else if (idx < S0 + S1) packT_one(Wl1, Wr1, Wc1, idx - S0, 85, 96, 56, 64);
        else if (idx < S0 + S1 + S2) packT_one(Wl2, Wr2, Wc2, idx - S0 - S1, 56, 64, 28, 32);
    } else {
        int i = (blockIdx.x - PACKB) * 256 + threadIdx.x;
        if (i < E) atomicAdd(&deg[edst[i]], 1);
    }
}

// ---- scans ----------------------------------------------------------------

__global__ void scanA_kernel(const int* __restrict__ deg, int* __restrict__ bsum, int N) {
    __shared__ int s[256];
    int i = blockIdx.x * 256 + threadIdx.x;
    s[threadIdx.x] = (i < N) ? deg[i] : 0;
    __syncthreads();
    for (int off = 128; off > 0; off >>= 1) {
        if (threadIdx.x < off) s[threadIdx.x] += s[threadIdx.x + off];
        __syncthreads();
    }
    if (threadIdx.x == 0) bsum[blockIdx.x] = s[0];
}

// scanC with inlined block-prefix: each block sums bsum[0..blockIdx.x).
__global__ void scanC_kernel(const int* __restrict__ deg, const int* __restrict__ bsum,
                             int* __restrict__ rowptr, int* __restrict__ cursor, int N, int E) {
    __shared__ int s[256];
    int t = threadIdx.x;

    int a = 0;
    for (int j = t; j < blockIdx.x; j += 256) a += bsum[j];
    s[t] = a;
    __syncthreads();
    for (int off = 128; off > 0; off >>= 1) {
        if (t < off) s[t] += s[t + off];
        __syncthreads();
    }
    const int base = s[0];
    __syncthreads();

    int i = blockIdx.x * 256 + t;
    int v = (i < N) ? deg[i] : 0;
    s[t] = v;
    __syncthreads();
    for (int off = 1; off < 256; off <<= 1) {
        int add = (t >= off) ? s[t - off] : 0;
        __syncthreads();
        s[t] += add;
        __syncthreads();
    }
    if (i < N) {
        int excl = base + s[t] - v;
        rowptr[i] = excl;
        cursor[i] = excl;
        if (i == N - 1) rowptr[N] = E;
    }
}

// ---- MFMA projection body: per-phase W in LDS + 2-phase epilogue ----------

template <bool XFP32, int KP, int SIN, int NTILES, int DOUT, int SPP>
__device__ __forceinline__ void
projm_body(int bid, const void* __restrict__ xin,
           const unsigned short* __restrict__ WcT,
           const float* __restrict__ bl,
           unsigned short* __restrict__ p,
           unsigned short* __restrict__ acc_out, int N) {
    constexpr int KT   = KP / 32;
    constexpr int HT   = NTILES / 2;
    constexpr int WSTR = KP + 8;
    constexpr int LSTR = SPP + 8;
    static_assert(HT * 16 == SPP, "phase width must equal SPP");
    __shared__ short wS[HT * 16 * WSTR];
    __shared__ short oS[128 * LSTR];

    const int lane = threadIdx.x & 63;
    const int wave = threadIdx.x >> 6;
    const int l15 = lane & 15;
    const int lk  = lane >> 4;
    const int row0 = bid * 128;
    const int wrow = wave * 32;

    auto stageW = [&](int colbase) {
        for (int c8 = threadIdx.x; c8 < HT * 16 * (KP / 8); c8 += 256) {
            const int c  = c8 / (KP / 8);
            const int k8 = c8 - c * (KP / 8);
            *(bf16x8*)(wS + c * WSTR + k8 * 8) =
                *(const bf16x8*)(WcT + (size_t)(colbase + c) * KP + k8 * 8);
        }
    };

    stageW(0);

    bf16x8 afrag[2][KT];
#pragma unroll
    for (int h = 0; h < 2; ++h) {
        int arow = row0 + wrow + h * 16 + l15;
        if (arow >= N) arow = N - 1;
        if constexpr (XFP32) {
            const float* xr = (const float*)xin + (size_t)arow * SIN + lk * 8;
#pragma unroll
            for (int kt = 0; kt < KT; ++kt) {
                const float4 a = *(const float4*)(xr + kt * 32);
                const float4 b = *(const float4*)(xr + kt * 32 + 4);
                bf16x8 v;
                v[0] = (short)f2bf(a.x); v[1] = (short)f2bf(a.y);
                v[2] = (short)f2bf(a.z); v[3] = (short)f2bf(a.w);
                v[4] = (short)f2bf(b.x); v[5] = (short)f2bf(b.y);
                v[6] = (short)f2bf(b.z); v[7] = (short)f2bf(b.w);
                afrag[h][kt] = v;
            }
        } else {
            const unsigned short* xr = (const unsigned short*)xin + (size_t)arow * SIN + lk * 8;
#pragma unroll
            for (int kt = 0; kt < KT; ++kt)
                afrag[h][kt] = *(const bf16x8*)(xr + kt * 32);
        }
    }

    __syncthreads();

    const int rows_here = min(128, N - row0);
    const int cnt8 = rows_here * (SPP / 8);

    auto computePhase = [&](bool withBias) {
#pragma unroll 2
        for (int nt = 0; nt < HT; ++nt) {
            const short* wp = wS + (size_t)(nt * 16 + l15) * WSTR + lk * 8;
            bf16x8 bfrag[KT];
#pragma unroll
            for (int kt = 0; kt < KT; ++kt)
                bfrag[kt] = *(const bf16x8*)(wp + kt * 32);

            f32x4 a0 = {0.f, 0.f, 0.f, 0.f};
            f32x4 a1 = {0.f, 0.f, 0.f, 0.f};
#pragma unroll
            for (int kt = 0; kt < KT; ++kt) {
                a0 = __builtin_amdgcn_mfma_f32_16x16x32_bf16(afrag[0][kt], bfrag[kt], a0, 0, 0, 0);
                a1 = __builtin_amdgcn_mfma_f32_16x16x32_bf16(afrag[1][kt], bfrag[kt], a1, 0, 0, 0);
            }

            const int co = nt * 16 + l15;
            const float bias = (withBias && co < DOUT) ? bl[co] : 0.0f;
#pragma unroll
            for (int h = 0; h < 2; ++h) {
                const f32x4 a = h ? a1 : a0;
                const int rl = wrow + h * 16 + lk * 4;
#pragma unroll
                for (int j = 0; j < 4; ++j)
                    oS[(rl + j) * LSTR + co] = (short)f2bf(a[j] + bias);
            }
        }
    };

    auto storeOut = [&](unsigned short* dst) {
        for (int e8 = threadIdx.x; e8 < cnt8; e8 += 256) {
            const int row = e8 / (SPP / 8);
            const int c8  = e8 - row * (SPP / 8);
            *(bf16x8*)(dst + (size_t)row0 * SPP + (size_t)e8 * 8) =
                *(const bf16x8*)(oS + row * LSTR + c8 * 8);
        }
    };

    computePhase(false);
    __syncthreads();
    storeOut(p);
    stageW(HT * 16);
    __syncthreads();
    computePhase(true);
    __syncthreads();
    storeOut(acc_out);
}

template <bool XFP32, int KP, int SIN, int NTILES, int DOUT, int SPP>
__global__ void __launch_bounds__(256)
projm_kernel(const void* __restrict__ xin,
             const unsigned short* __restrict__ WcT,
             const float* __restrict__ bl,
             unsigned short* __restrict__ p,
             unsigned short* __restrict__ acc_out, int N) {
    projm_body<XFP32, KP, SIN, NTILES, DOUT, SPP>(blockIdx.x, xin, WcT, bl, p, acc_out, N);
}

// ---- fused: XCD-partitioned CSR fill (blocks [0,FILLB)) || projm L0 -------
// FILLB=512 so initial residency is ~512 fill + ~256 projm (both roles live
// from t=0). Fill partition p = bid%8 owns dst range [p*N/8, ...); sub-blocks
// grid-stride the edge list and filter. Correctness independent of mapping.

__global__ void __launch_bounds__(256)
projfill_kernel(const float* __restrict__ x,
                const unsigned short* __restrict__ Wc0,
                const float* __restrict__ bl0,
                unsigned short* __restrict__ p,
                unsigned short* __restrict__ acc_out, int N,
                const int* __restrict__ esrc, const int* __restrict__ edst,
                int* __restrict__ cursor, int* __restrict__ csr, int E) {
    if (blockIdx.x < FILLB) {
        const int part = blockIdx.x & 7;
        const int sub  = blockIdx.x >> 3;
        const int nsub = FILLB >> 3;
        const int chunk = N >> 3;
        const int lo = part * chunk;
        const int hi = (part == 7) ? N : lo + chunk;
        for (int i = sub * 256 + threadIdx.x; i < E; i += nsub * 256) {
            const int d = edst[i];
            if (d >= lo && d < hi) {
                int pos = atomicAdd(&cursor[d], 1);
                csr[pos] = esrc[i];
            }
        }
        return;
    }
    projm_body<true, 128, 128, 12, 85, 96>(blockIdx.x - FILLB, x, Wc0, bl0, p, acc_out, N);
}

// ---- gather: x_next = bf16(acc + invdeg * sum p[src]) ---------------------

template <int DOUT, int SP, int SN, int NPW>
__global__ void __launch_bounds__(256)
gatherb_kernel(const int* __restrict__ rowptr, const int* __restrict__ csr,
               const unsigned short* __restrict__ p, const unsigned short* __restrict__ acc,
               unsigned short* __restrict__ xnext, int N) {
    const int wid  = (blockIdx.x * 256 + threadIdx.x) >> 6;
    const int lane = threadIdx.x & 63;
    int node, hl;
    if constexpr (NPW == 1) {
        node = __builtin_amdgcn_readfirstlane(wid);
        hl = lane;
    } else {
        node = wid * 2 + (lane >> 5);
        hl = lane & 31;
    }
    if (node >= N) return;
    const int beg = rowptr[node], end = rowptr[node + 1];
    const float inv = 1.0f / (float)max(end - beg, 1);
    constexpr int NPAIR = (DOUT + 1) / 2;
    const int co = 2 * hl;

    float s0 = 0.f, s1 = 0.f, s2 = 0.f, s3 = 0.f;
    float h0 = 0.f, h1 = 0.f, h2 = 0.f, h3 = 0.f;
    if (hl < NPAIR) {
        int j = beg;
        for (; j + 4 <= end; j += 4) {
            const unsigned u0 = *(const unsigned*)(p + (size_t)csr[j]     * SP + co);
            const unsigned u1 = *(const unsigned*)(p + (size_t)csr[j + 1] * SP + co);
            const unsigned u2 = *(const unsigned*)(p + (size_t)csr[j + 2] * SP + co);
            const unsigned u3 = *(const unsigned*)(p + (size_t)csr[j + 3] * SP + co);
            s0 += bf2f(u0 & 0xffffu); h0 += bf2f(u0 >> 16);
            s1 += bf2f(u1 & 0xffffu); h1 += bf2f(u1 >> 16);
            s2 += bf2f(u2 & 0xffffu); h2 += bf2f(u2 >> 16);
            s3 += bf2f(u3 & 0xffffu); h3 += bf2f(u3 >> 16);
        }
        for (; j < end; ++j) {
            const unsigned u0 = *(const unsigned*)(p + (size_t)csr[j] * SP + co);
            s0 += bf2f(u0 & 0xffffu); h0 += bf2f(u0 >> 16);
        }
    }
    if (co < SN) {
        const float slo = (s0 + s1) + (s2 + s3);
        const float shi = (h0 + h1) + (h2 + h3);
        float lo = 0.f, hi = 0.f;
        if (co < DOUT)     lo = bf2f((unsigned)acc[(size_t)node * SP + co])     + inv * slo;
        if (co + 1 < DOUT) hi = bf2f((unsigned)acc[(size_t)node * SP + co + 1]) + inv * shi;
        const unsigned w = (unsigned)f2bf(lo) | ((unsigned)f2bf(hi) << 16);
        *(unsigned*)(xnext + (size_t)node * SN + co) = w;
    }
}

// ---- layer-2 gather fused with layer-3 GEMV (28 -> 1), 2 nodes/wave -------

__global__ void __launch_bounds__(256)
gather2g_kernel(const int* __restrict__ rowptr, const int* __restrict__ csr,
                const unsigned short* __restrict__ p, const unsigned short* __restrict__ acc,
                const float* __restrict__ Wl3, const float* __restrict__ bl3,
                const float* __restrict__ Wr3,
                float* __restrict__ p3, float* __restrict__ out, int N) {
    const int wid  = (blockIdx.x * 256 + threadIdx.x) >> 6;
    const int lane = threadIdx.x & 63;
    const int node = wid * 2 + (lane >> 5);
    const int hl   = lane & 31;
    if (node >= N) return;
    const int beg = rowptr[node], end = rowptr[node + 1];
    const float inv = 1.0f / (float)max(end - beg, 1);
    const int co = 2 * hl;

    float s0 = 0.f, s1 = 0.f, s2 = 0.f, s3 = 0.f;
    float h0 = 0.f, h1 = 0.f, h2 = 0.f, h3 = 0.f;
    if (hl < 14) {
        int j = beg;
        for (; j + 4 <= end; j += 4) {
            const unsigned u0 = *(const unsigned*)(p + (size_t)csr[j]     * 32 + co);
            const unsigned u1 = *(const unsigned*)(p + (size_t)csr[j + 1] * 32 + co);
            const unsigned u2 = *(const unsigned*)(p + (size_t)csr[j + 2] * 32 + co);
            const unsigned u3 = *(const unsigned*)(p + (size_t)csr[j + 3] * 32 + co);
            s0 += bf2f(u0 & 0xffffu); h0 += bf2f(u0 >> 16);
            s1 += bf2f(u1 & 0xffffu); h1 += bf2f(u1 >> 16);
            s2 += bf2f(u2 & 0xffffu); h2 += bf2f(u2 >> 16);
            s3 += bf2f(u3 & 0xffffu); h3 += bf2f(u3 >> 16);
        }
        for (; j < end; ++j) {
            const unsigned u0 = *(const unsigned*)(p + (size_t)csr[j] * 32 + co);
            s0 += bf2f(u0 & 0xffffu); h0 += bf2f(u0 >> 16);
        }
    }
    float xlo = 0.f, xhi = 0.f, wl0 = 0.f, wl1 = 0.f, wr0 = 0.f, wr1 = 0.f;
    if (hl < 14) {
        xlo = bf2f((unsigned)acc[(size_t)node * 32 + co])     + inv * ((s0 + s1) + (s2 + s3));
        xhi = bf2f((unsigned)acc[(size_t)node * 32 + co + 1]) + inv * ((h0 + h1) + (h2 + h3));
        wl0 = Wl3[co]; wl1 = Wl3[co + 1];
        wr0 = Wr3[co]; wr1 = Wr3[co + 1];
    }
    float sl = xlo * wl0 + xhi * wl1;
    float sr = xlo * wr0 + xhi * wr1;
#pragma unroll
    for (int off = 16; off > 0; off >>= 1) {
        sl += __shfl_xor(sl, off, 64);
        sr += __shfl_xor(sr, off, 64);
    }
    if (hl == 0) {
        p3[node] = sl;
        out[node] = sr + bl3[0];
    }
}

__global__ void gather1_kernel(const int* __restrict__ rowptr, const int* __restrict__ csr,
                               const float* __restrict__ p, float* __restrict__ out, int N) {
    const int node = blockIdx.x * blockDim.x + threadIdx.x;
    if (node >= N) return;
    const int beg = rowptr[node], end = rowptr[node + 1];
    const float inv = 1.0f / (float)max(end - beg, 1);
    float a0 = 0.f, a1 = 0.f, a2 = 0.f, a3 = 0.f;
    int j = beg;
    for (; j + 4 <= end; j += 4) {
        a0 += p[csr[j]]; a1 += p[csr[j + 1]]; a2 += p[csr[j + 2]]; a3 += p[csr[j + 3]];
    }
    for (; j < end; ++j) a0 += p[csr[j]];
    out[node] += inv * ((a0 + a1) + (a2 + a3));
}

// ---------------------------------------------------------------------------

extern "C" void kernel_launch(void* const* d_in, const int* in_sizes, int n_in,
                              void* d_out, int out_size, void* d_ws, size_t ws_size,
                              hipStream_t stream) {
    const float* x  = (const float*)d_in[0];
    const int*   ei = (const int*)d_in[1];
    const int N = NNODES;
    const int E = NEDGES;
    const int* esrc = ei;
    const int* edst = ei + E;

    const float* Wl[4] = {(const float*)d_in[2], (const float*)d_in[5],
                          (const float*)d_in[8], (const float*)d_in[11]};
    const float* bl[4] = {(const float*)d_in[3], (const float*)d_in[6],
                          (const float*)d_in[9], (const float*)d_in[12]};
    const float* Wr[4] = {(const float*)d_in[4], (const float*)d_in[7],
                          (const float*)d_in[10], (const float*)d_in[13]};

    // ---- workspace arena (byte offsets, 256B aligned) ----
    char* base = (char*)d_ws;
    size_t off = 0;
    auto alloc = [&](size_t bytes) {
        char* r = base + off;
        off += (bytes + 255) & ~(size_t)255;
        return r;
    };
    unsigned short* pB   = (unsigned short*)alloc((size_t)N * 96 * 2);
    unsigned short* accB = (unsigned short*)alloc((size_t)N * 96 * 2);
    unsigned short* xp   = (unsigned short*)alloc((size_t)N * 96 * 2);
    float*          p3   = (float*)alloc((size_t)N * 4);
    unsigned short* Wc0  = (unsigned short*)alloc((size_t)192 * 128 * 2);
    unsigned short* Wc1  = (unsigned short*)alloc((size_t)128 * 96 * 2);
    unsigned short* Wc2  = (unsigned short*)alloc((size_t)64 * 64 * 2);
    int* degi   = (int*)alloc((size_t)N * 4);
    int* rowptr = (int*)alloc((size_t)(N + 1) * 4);
    int* cursor = (int*)alloc((size_t)N * 4);
    int* csr    = (int*)alloc((size_t)E * 4);
    int* bsum   = (int*)alloc(512 * 4);

    unsigned short* x2 = xp;   // x1 dead after L1 proj; reuse region for x2

    const int nb = (N + 255) / 256;     // 391
    const int histB = (E + 255) / 256;  // 2500
    const int projBlocks = (N + 127) / 128;  // 782

    // degi = 0, then fused {packAll || hist}
    hipMemsetAsync(degi, 0, (size_t)N * sizeof(int), stream);
    packhist_kernel<<<PACKB + histB, 256, 0, stream>>>(
        Wl[0], Wr[0], Wl[1], Wr[1], Wl[2], Wr[2], Wc0, Wc1, Wc2, edst, degi, E);

    // scans (scanB folded into scanC)
    scanA_kernel<<<nb, 256, 0, stream>>>(degi, bsum, N);
    scanC_kernel<<<nb, 256, 0, stream>>>(degi, bsum, rowptr, cursor, N, E);

    // fused {partitioned fill (512 blocks) || projm L0}
    projfill_kernel<<<FILLB + projBlocks, 256, 0, stream>>>(
        x, Wc0, bl[0], pB, accB, N, esrc, edst, cursor, csr, E);
    gatherb_kernel<85, 96, 96, 1><<<(N + 3) / 4, 256, 0, stream>>>(
        rowptr, csr, pB, accB, xp, N);

    // Layer 1: K=96 (85 zero-padded), 8 tiles (4+4); p/acc stride 64
    projm_kernel<false, 96, 96, 8, 56, 64><<<projBlocks, 256, 0, stream>>>(
        xp, Wc1, bl[1], pB, accB, N);
    gatherb_kernel<56, 64, 64, 2><<<(N + 7) / 8, 256, 0, stream>>>(
        rowptr, csr, pB, accB, x2, N);

    // Layer 2: K=64 (56 zero-padded), 4 tiles (2+2); p/acc stride 32
    projm_kernel<false, 64, 64, 4, 28, 32><<<projBlocks, 256, 0, stream>>>(
        x2, Wc2, bl[2], pB, accB, N);

    // Layer-2 gather + layer-3 GEMV fused (2 nodes/wave); then scalar gather
    gather2g_kernel<<<(N + 7) / 8, 256, 0, stream>>>(
        rowptr, csr, pB, accB, Wl[3], bl[3], Wr[3], p3, (float*)d_out, N);
    gather1_kernel<<<(N + 255) / 256, 256, 0, stream>>>(
        rowptr, csr, p3, (float*)d_out, N);
}